// Round 2
// baseline (206.710 us; speedup 1.0000x reference)
//
#include <hip/hip_runtime.h>
#include <cstdint>
#include <cstddef>

using bf16 = __bf16;
typedef float f32x4 __attribute__((ext_vector_type(4)));
typedef __bf16 bf16x8v __attribute__((ext_vector_type(8)));
typedef __bf16 bf16x4v __attribute__((ext_vector_type(4)));

// Problem constants: B=4, S=2048, D=1024
#define NX   8388608      // 4*2048*1024
#define NW   1048576      // 1024*1024
#define SB   2048
#define DD   1024

__device__ __forceinline__ void gload_lds16(const bf16* g, bf16* l) {
    __builtin_amdgcn_global_load_lds(
        (const __attribute__((address_space(1))) void*)(g),
        (__attribute__((address_space(3))) void*)(l), 16, 0, 0);
}

// ---------------------------------------------------------------------------
// Convert fp32 inputs -> bf16 in workspace; copy biases (fp32) contiguous.
// ---------------------------------------------------------------------------
__global__ __launch_bounds__(256)
void convert_kernel(const float* __restrict__ x1,
                    const float* __restrict__ Wq, const float* __restrict__ Wk,
                    const float* __restrict__ Wv,
                    const float* __restrict__ bq, const float* __restrict__ bk,
                    const float* __restrict__ bv,
                    bf16* __restrict__ xb, bf16* __restrict__ wb,
                    float* __restrict__ biases)
{
    const int NX4 = NX / 4;
    const int NW4 = NW / 4;
    const int NMAT = NX4 + 3 * NW4;
    const int total = NMAT + 768;
    for (int i = blockIdx.x * 256 + threadIdx.x; i < total; i += gridDim.x * 256) {
        if (i < NMAT) {
            const float* src; bf16* dst; int j;
            if (i < NX4) { src = x1; dst = xb; j = i; }
            else {
                int w = (i - NX4) / NW4;
                j = (i - NX4) - w * NW4;
                src = (w == 0) ? Wq : (w == 1) ? Wk : Wv;
                dst = wb + (size_t)w * NW;
            }
            float4 f = ((const float4*)src)[j];
            bf16x4v o;
            o[0] = (bf16)f.x; o[1] = (bf16)f.y; o[2] = (bf16)f.z; o[3] = (bf16)f.w;
            ((bf16x4v*)dst)[j] = o;
        } else {
            int j = i - NMAT;
            const float* src = (j < 256) ? bq : (j < 512) ? bk : bv;
            ((float4*)biases)[j] = ((const float4*)src)[j & 255];
        }
    }
}

// ---------------------------------------------------------------------------
// Stage one 16 KiB K-half (256 rows x 32 bf16) global -> LDS (linear dest,
// inverse-swizzled per-lane global source). 2 x global_load_lds per thread.
// LDS half layout: [256 rows][4 chunks of 8 bf16], chunk slot c holds global
// chunk g = c ^ s(r), s(r) = (r + (r>>2)) & 3.
// ---------------------------------------------------------------------------
__device__ __forceinline__ void stage_half(const bf16* __restrict__ g0, int ldg,
                                           bf16* l0, int wid, int lane)
{
    #pragma unroll
    for (int j = 0; j < 2; ++j) {
        const int ci = wid * 128 + j * 64 + lane;   // 0..511, lane-consecutive
        const int r  = ci >> 2;
        const int c  = ci & 3;
        const int s  = (r + (r >> 2)) & 3;
        gload_lds16(g0 + (size_t)r * ldg + ((c ^ s) << 3), l0 + ci * 8);
    }
}

// ---------------------------------------------------------------------------
// 256x256 tile, BK=64 (2 K-halves of 32), 8 waves (2M x 4N), 512 threads.
// 4 phases per K-tile: phase = (kk, mh): 16 MFMA each; one half-tile stage
// per phase; counted vmcnt(4) once per tile (never 0 until the tail).
// C[m][n] = scale * sum_k A[m][k]*B[n][k]  (A: MxK, B: NxK, both row-major).
// V=0: QKV fused (N=3072; bias; q/k normal, v written transposed [b][d][s])
// V=1: bf16 out, scaled        V=2: f32 out
// ---------------------------------------------------------------------------
template<int V, typename OutT>
__global__ __launch_bounds__(512, 2)
void gemm256(const bf16* __restrict__ A, const bf16* __restrict__ B,
             OutT* __restrict__ C, bf16* __restrict__ vT,
             const float* __restrict__ bias,
             int N, int K, int NXT,
             long sA, long sB, long sC, float scale)
{
    __shared__ bf16 sh[2][2][2][8192];   // [buf][A/B][kk][256*32] = 128 KiB
    const int z = blockIdx.z;
    A += (size_t)z * sA; B += (size_t)z * sB; C += (size_t)z * sC;

    // XCD-aware bijective swizzle (gridDim.x % 8 == 0 for all our launches)
    const int nwg = gridDim.x;
    const int qq = nwg >> 3;
    const int bid = ((int)blockIdx.x & 7) * qq + ((int)blockIdx.x >> 3);
    const int bx = bid % NXT, by = bid / NXT;
    const int n0 = bx * 256, m0 = by * 256;

    const int tid = threadIdx.x;
    const int lane = tid & 63, wid = tid >> 6;
    const int wr = wid >> 2, wc = wid & 3;

    const bf16* Ag = A + (size_t)m0 * K;
    const bf16* Bg = B + (size_t)n0 * K;

    // per-lane ds_read offsets (elements within a K-half)
    const int rl = lane & 15, lg = lane >> 4;
    const int RA0 = wr * 128 + rl;
    const int cA = lg ^ ((RA0 + (RA0 >> 2)) & 3);
    const int offA = RA0 * 32 + cA * 8;
    const int RB0 = wc * 64 + rl;
    const int cB = lg ^ ((RB0 + (RB0 >> 2)) & 3);
    const int offB = RB0 * 32 + cB * 8;

    f32x4 acc[8][4];
    #pragma unroll
    for (int m = 0; m < 8; ++m)
        #pragma unroll
        for (int n = 0; n < 4; ++n) acc[m][n] = (f32x4){0.f, 0.f, 0.f, 0.f};

    const int NT = K >> 6;

    // prologue: tile0 fully + tile1 k0-halves; keep 2 halves in flight
    stage_half(Ag,      K, &sh[0][0][0][0], wid, lane);   // t0.Ak0
    stage_half(Bg,      K, &sh[0][1][0][0], wid, lane);   // t0.Bk0
    stage_half(Ag + 32, K, &sh[0][0][1][0], wid, lane);   // t0.Ak1
    stage_half(Bg + 32, K, &sh[0][1][1][0], wid, lane);   // t0.Bk1
    stage_half(Ag + 64, K, &sh[1][0][0][0], wid, lane);   // t1.Ak0
    stage_half(Bg + 64, K, &sh[1][1][0][0], wid, lane);   // t1.Bk0
    asm volatile("s_waitcnt vmcnt(4)" ::: "memory");      // t0 resident
    __builtin_amdgcn_s_barrier();

    for (int t = 0; t < NT; ++t) {
        const int buf = t & 1;
        const bf16* lA0 = &sh[buf][0][0][0];
        const bf16* lA1 = &sh[buf][0][1][0];
        const bf16* lB0 = &sh[buf][1][0][0];
        const bf16* lB1 = &sh[buf][1][1][0];
        bf16x8v af[4], bfr[4];

        // ---- phase 0: kk=0, mh=0 ----
        #pragma unroll
        for (int i = 0; i < 4; ++i) af[i] = *(const bf16x8v*)(lA0 + offA + i * 512);
        #pragma unroll
        for (int n = 0; n < 4; ++n) bfr[n] = *(const bf16x8v*)(lB0 + offB + n * 512);
        if (t + 1 < NT) stage_half(Ag + (t + 1) * 64 + 32, K, &sh[buf ^ 1][0][1][0], wid, lane);
        __builtin_amdgcn_s_barrier();
        asm volatile("s_waitcnt lgkmcnt(0)" ::: "memory");
        __builtin_amdgcn_s_setprio(1);
        #pragma unroll
        for (int i = 0; i < 4; ++i)
            #pragma unroll
            for (int n = 0; n < 4; ++n)
                acc[i][n] = __builtin_amdgcn_mfma_f32_16x16x32_bf16(af[i], bfr[n], acc[i][n], 0, 0, 0);
        __builtin_amdgcn_s_setprio(0);
        __builtin_amdgcn_s_barrier();

        // ---- phase 1: kk=0, mh=1 ----
        #pragma unroll
        for (int i = 0; i < 4; ++i) af[i] = *(const bf16x8v*)(lA0 + offA + (4 + i) * 512);
        if (t + 1 < NT) stage_half(Bg + (t + 1) * 64 + 32, K, &sh[buf ^ 1][1][1][0], wid, lane);
        __builtin_amdgcn_s_barrier();
        asm volatile("s_waitcnt lgkmcnt(0)" ::: "memory");
        __builtin_amdgcn_s_setprio(1);
        #pragma unroll
        for (int i = 0; i < 4; ++i)
            #pragma unroll
            for (int n = 0; n < 4; ++n)
                acc[4 + i][n] = __builtin_amdgcn_mfma_f32_16x16x32_bf16(af[i], bfr[n], acc[4 + i][n], 0, 0, 0);
        __builtin_amdgcn_s_setprio(0);
        __builtin_amdgcn_s_barrier();

        // ---- phase 2: kk=1, mh=0 ----
        #pragma unroll
        for (int i = 0; i < 4; ++i) af[i] = *(const bf16x8v*)(lA1 + offA + i * 512);
        #pragma unroll
        for (int n = 0; n < 4; ++n) bfr[n] = *(const bf16x8v*)(lB1 + offB + n * 512);
        if (t + 2 < NT) stage_half(Ag + (t + 2) * 64, K, &sh[buf][0][0][0], wid, lane);
        __builtin_amdgcn_s_barrier();
        asm volatile("s_waitcnt lgkmcnt(0)" ::: "memory");
        __builtin_amdgcn_s_setprio(1);
        #pragma unroll
        for (int i = 0; i < 4; ++i)
            #pragma unroll
            for (int n = 0; n < 4; ++n)
                acc[i][n] = __builtin_amdgcn_mfma_f32_16x16x32_bf16(af[i], bfr[n], acc[i][n], 0, 0, 0);
        __builtin_amdgcn_s_setprio(0);
        __builtin_amdgcn_s_barrier();

        // ---- phase 3: kk=1, mh=1 ----
        #pragma unroll
        for (int i = 0; i < 4; ++i) af[i] = *(const bf16x8v*)(lA1 + offA + (4 + i) * 512);
        if (t + 2 < NT) stage_half(Bg + (t + 2) * 64, K, &sh[buf][1][0][0], wid, lane);
        if (t == NT - 2)      asm volatile("s_waitcnt vmcnt(0)" ::: "memory");
        else if (t < NT - 2)  asm volatile("s_waitcnt vmcnt(4)" ::: "memory");
        __builtin_amdgcn_s_barrier();
        asm volatile("s_waitcnt lgkmcnt(0)" ::: "memory");
        __builtin_amdgcn_s_setprio(1);
        #pragma unroll
        for (int i = 0; i < 4; ++i)
            #pragma unroll
            for (int n = 0; n < 4; ++n)
                acc[4 + i][n] = __builtin_amdgcn_mfma_f32_16x16x32_bf16(af[i], bfr[n], acc[4 + i][n], 0, 0, 0);
        __builtin_amdgcn_s_setprio(0);
        __builtin_amdgcn_s_barrier();
    }

    // epilogue: C/D map col=lane&15, row=(lane>>4)*4+reg
    const int ci = rl;
    const int ri = lg << 2;
    #pragma unroll
    for (int m = 0; m < 8; ++m) {
        const int gm = m0 + wr * 128 + m * 16 + ri;
        #pragma unroll
        for (int n = 0; n < 4; ++n) {
            const int col = n0 + wc * 64 + n * 16 + ci;
            if constexpr (V == 0) {
                const float bb = bias[col];
                if (col < 1024) {
                    #pragma unroll
                    for (int r = 0; r < 4; ++r)
                        C[(size_t)(gm + r) * 1024 + col] = (OutT)(acc[m][n][r] + bb);
                } else if (col < 2048) {
                    #pragma unroll
                    for (int r = 0; r < 4; ++r)
                        C[NX + (size_t)(gm + r) * 1024 + (col - 1024)] = (OutT)(acc[m][n][r] + bb);
                } else {
                    const int batch = gm >> 11, s = gm & 2047, d = col - 2048;
                    bf16x4v pk;
                    #pragma unroll
                    for (int r = 0; r < 4; ++r) pk[r] = (bf16)(acc[m][n][r] + bb);
                    *(bf16x4v*)&vT[((size_t)batch << 21) + ((size_t)d << 11) + s] = pk;
                }
            } else {
                #pragma unroll
                for (int r = 0; r < 4; ++r)
                    C[(size_t)(gm + r) * N + col] = (OutT)(acc[m][n][r] * scale);
            }
        }
    }
}

// ---------------------------------------------------------------------------
// Row softmax in-place over bf16 scores; rows of length 2048, 1 block/row.
// ---------------------------------------------------------------------------
__global__ __launch_bounds__(256)
void softmax_inplace(bf16* __restrict__ sc)
{
    __shared__ float red[8];
    bf16* row = sc + (size_t)blockIdx.x * 2048;
    const int t = threadIdx.x;
    const int lane = t & 63;
    const int wid = t >> 6;

    bf16x8v v = *(const bf16x8v*)(row + t * 8);
    float f[8];
    #pragma unroll
    for (int j = 0; j < 8; ++j) f[j] = (float)v[j];

    float m = f[0];
    #pragma unroll
    for (int j = 1; j < 8; ++j) m = fmaxf(m, f[j]);
    #pragma unroll
    for (int off = 32; off >= 1; off >>= 1) m = fmaxf(m, __shfl_xor(m, off));
    if (lane == 0) red[wid] = m;
    __syncthreads();
    m = fmaxf(fmaxf(red[0], red[1]), fmaxf(red[2], red[3]));

    float s = 0.f;
    #pragma unroll
    for (int j = 0; j < 8; ++j) { f[j] = __expf(f[j] - m); s += f[j]; }
    #pragma unroll
    for (int off = 32; off >= 1; off >>= 1) s += __shfl_xor(s, off);
    if (lane == 0) red[4 + wid] = s;
    __syncthreads();
    s = red[4] + red[5] + red[6] + red[7];

    const float inv = 1.0f / s;
    bf16x8v o;
    #pragma unroll
    for (int j = 0; j < 8; ++j) o[j] = (bf16)(f[j] * inv);
    *(bf16x8v*)(row + t * 8) = o;
}

// ---------------------------------------------------------------------------
extern "C" void kernel_launch(void* const* d_in, const int* in_sizes, int n_in,
                              void* d_out, int out_size, void* d_ws, size_t ws_size,
                              hipStream_t stream)
{
    const float* x1 = (const float*)d_in[0];
    const float* Wq = (const float*)d_in[1];
    const float* bq = (const float*)d_in[2];
    const float* Wk = (const float*)d_in[3];
    const float* bk = (const float*)d_in[4];
    const float* Wv = (const float*)d_in[5];
    const float* bv = (const float*)d_in[6];
    float* out = (float*)d_out;

    // workspace layout (bf16 elements unless noted)
    bf16* xb     = (bf16*)d_ws;             // 8388608
    bf16* wb     = xb + NX;                 // 3*1048576 (Wq,Wk,Wv rows x 1024)
    bf16* qkb    = wb + 3 * NW;             // 2*8388608 (q then k)
    bf16* vTb    = qkb + 2 * (size_t)NX;    // 8388608 (V^T per batch [D][S])
    bf16* scores = vTb + NX;                // 4*2048*2048
    float* biases = (float*)(scores + 4 * (size_t)SB * SB); // 3072 f32

    // 1. convert inputs to bf16
    convert_kernel<<<dim3(2048), dim3(256), 0, stream>>>(
        x1, Wq, Wk, Wv, bq, bk, bv, xb, wb, biases);

    // 2. fused QKV projection: M=8192, N=3072 (q|k|vT), K=1024
    gemm256<0, bf16><<<dim3(384, 1, 1), dim3(512), 0, stream>>>(
        xb, wb, qkb, vTb, biases, 1024, 1024, 12, 0L, 0L, 0L, 1.0f);

    // 3. scores = Q K^T / 32 per batch: M=N=2048, K=1024, z=4
    gemm256<1, bf16><<<dim3(64, 1, 4), dim3(512), 0, stream>>>(
        qkb, qkb + NX, scores, nullptr, nullptr, 2048, 1024, 8,
        (long)(SB * DD), (long)(SB * DD), (long)(SB * SB), 1.0f / 32.0f);

    // 4. softmax rows in-place
    softmax_inplace<<<dim3(4 * SB), dim3(256), 0, stream>>>(scores);

    // 5. out = P V per batch: M=2048, N=1024, K=2048, z=4, fp32 out
    gemm256<2, float><<<dim3(32, 1, 4), dim3(512), 0, stream>>>(
        scores, vTb, out, nullptr, nullptr, 1024, 2048, 4,
        (long)(SB * SB), (long)(SB * DD), (long)(SB * DD), 1.0f);
}

// Round 3
// 185.819 us; speedup vs baseline: 1.1124x; 1.1124x over previous
//
#include <hip/hip_runtime.h>
#include <cstdint>
#include <cstddef>

using bf16 = __bf16;
typedef float f32x4 __attribute__((ext_vector_type(4)));
typedef __bf16 bf16x8v __attribute__((ext_vector_type(8)));
typedef __bf16 bf16x4v __attribute__((ext_vector_type(4)));

// Problem constants: B=4, S=2048, D=1024
#define NX   8388608      // 4*2048*1024
#define NW   1048576      // 1024*1024
#define SB   2048
#define DD   1024

__device__ __forceinline__ void gload_lds16(const bf16* g, bf16* l) {
    __builtin_amdgcn_global_load_lds(
        (const __attribute__((address_space(1))) void*)(g),
        (__attribute__((address_space(3))) void*)(l), 16, 0, 0);
}

// ---------------------------------------------------------------------------
// Convert fp32 inputs -> bf16 in workspace; copy biases (fp32) contiguous.
// ---------------------------------------------------------------------------
__global__ __launch_bounds__(256)
void convert_kernel(const float* __restrict__ x1,
                    const float* __restrict__ Wq, const float* __restrict__ Wk,
                    const float* __restrict__ Wv,
                    const float* __restrict__ bq, const float* __restrict__ bk,
                    const float* __restrict__ bv,
                    bf16* __restrict__ xb, bf16* __restrict__ wb,
                    float* __restrict__ biases)
{
    const int NX4 = NX / 4;
    const int NW4 = NW / 4;
    const int NMAT = NX4 + 3 * NW4;
    const int total = NMAT + 768;
    for (int i = blockIdx.x * 256 + threadIdx.x; i < total; i += gridDim.x * 256) {
        if (i < NMAT) {
            const float* src; bf16* dst; int j;
            if (i < NX4) { src = x1; dst = xb; j = i; }
            else {
                int w = (i - NX4) / NW4;
                j = (i - NX4) - w * NW4;
                src = (w == 0) ? Wq : (w == 1) ? Wk : Wv;
                dst = wb + (size_t)w * NW;
            }
            float4 f = ((const float4*)src)[j];
            bf16x4v o;
            o[0] = (bf16)f.x; o[1] = (bf16)f.y; o[2] = (bf16)f.z; o[3] = (bf16)f.w;
            ((bf16x4v*)dst)[j] = o;
        } else {
            int j = i - NMAT;
            const float* src = (j < 256) ? bq : (j < 512) ? bk : bv;
            ((float4*)biases)[j] = ((const float4*)src)[j & 255];
        }
    }
}

// ---------------------------------------------------------------------------
// GEMM: C[m][n] = scale * sum_k A[m][k]*B[n][k] (+ bias[n])
// A: M x K row-major bf16, B: N x K row-major bf16 (both K-contiguous).
// 128x128 tile, BK=64, 4 waves (2x2 of 64x64), mfma_f32_16x16x32_bf16.
// LDS XOR-swizzle (chunk ^= row&7) via pre-swizzled global source (linear
// LDS dest for global_load_lds) + swizzled ds_read. Verified conflict-free
// in round 1 (SQ_LDS_BANK_CONFLICT = 0).
// XCD-aware bijective block swizzle on the flattened (x,y) grid (nwg%8==0).
// V=0: fused QKV epilogue (bias; col<1024 -> q, <2048 -> k, else v written
//      transposed [b][d][s]).   V=1: bf16 out, scaled.   V=2: f32 out.
// ---------------------------------------------------------------------------
template<int V, typename OutT>
__global__ __launch_bounds__(256)
void gemm_bt(const bf16* __restrict__ A, const bf16* __restrict__ B,
             OutT* __restrict__ C, bf16* __restrict__ vT,
             const float* __restrict__ bias,
             int N, int K,
             long sAz, long sBz, long sCz, float scale)
{
    __shared__ bf16 lA[128 * 64];
    __shared__ bf16 lB[128 * 64];
    const int z = blockIdx.z;
    A += (size_t)z * sAz;
    B += (size_t)z * sBz;
    C += (size_t)z * sCz;

    // T1: XCD-aware bijective swizzle of the flattened 2D grid
    const int gx = gridDim.x;
    const int nwg = gx * gridDim.y;
    const int orig = (int)blockIdx.y * gx + (int)blockIdx.x;
    const int q8 = nwg >> 3;
    const int tile = (orig & 7) * q8 + (orig >> 3);
    const int bx = tile % gx;
    const int by = tile / gx;

    const int n0 = bx * 128;
    const int m0 = by * 128;
    const int t = threadIdx.x;
    const int lane = t & 63;
    const int wid = t >> 6;
    const int wr = wid >> 1, wc = wid & 1;

    f32x4 acc[4][4];
    #pragma unroll
    for (int m = 0; m < 4; ++m)
        #pragma unroll
        for (int n = 0; n < 4; ++n) acc[m][n] = (f32x4){0.f, 0.f, 0.f, 0.f};

    for (int k0 = 0; k0 < K; k0 += 64) {
        #pragma unroll
        for (int l = 0; l < 4; ++l) {
            const int idx = l * 256 + t;
            const int row = idx >> 3;
            const int c   = idx & 7;
            const int gc  = c ^ (row & 7);   // inverse-swizzled source chunk
            gload_lds16(A + (size_t)(m0 + row) * K + k0 + gc * 8, &lA[idx * 8]);
            gload_lds16(B + (size_t)(n0 + row) * K + k0 + gc * 8, &lB[idx * 8]);
        }
        __syncthreads();
        #pragma unroll
        for (int kk = 0; kk < 2; ++kk) {
            bf16x8v af[4], bfr[4];
            #pragma unroll
            for (int m = 0; m < 4; ++m) {
                const int row = wr * 64 + m * 16 + (lane & 15);
                const int ch  = (kk * 4 + (lane >> 4)) ^ (row & 7);
                af[m] = *(const bf16x8v*)&lA[row * 64 + ch * 8];
            }
            #pragma unroll
            for (int n = 0; n < 4; ++n) {
                const int row = wc * 64 + n * 16 + (lane & 15);
                const int ch  = (kk * 4 + (lane >> 4)) ^ (row & 7);
                bfr[n] = *(const bf16x8v*)&lB[row * 64 + ch * 8];
            }
            #pragma unroll
            for (int m = 0; m < 4; ++m)
                #pragma unroll
                for (int n = 0; n < 4; ++n)
                    acc[m][n] = __builtin_amdgcn_mfma_f32_16x16x32_bf16(
                        af[m], bfr[n], acc[m][n], 0, 0, 0);
        }
        __syncthreads();
    }

    // epilogue: C/D map col=lane&15, row=(lane>>4)*4+reg (m89-verified)
    const int cif = lane & 15;
    const int rif = (lane >> 4) << 2;
    #pragma unroll
    for (int m = 0; m < 4; ++m) {
        const int gm = m0 + wr * 64 + m * 16 + rif;
        #pragma unroll
        for (int n = 0; n < 4; ++n) {
            const int col = n0 + wc * 64 + n * 16 + cif;
            if constexpr (V == 0) {
                const float bb = bias[col];
                if (col < 1024) {
                    #pragma unroll
                    for (int r = 0; r < 4; ++r)
                        C[(size_t)(gm + r) * 1024 + col] = (OutT)(acc[m][n][r] + bb);
                } else if (col < 2048) {
                    #pragma unroll
                    for (int r = 0; r < 4; ++r)
                        C[NX + (size_t)(gm + r) * 1024 + (col - 1024)] = (OutT)(acc[m][n][r] + bb);
                } else {
                    const int batch = gm >> 11, s = gm & 2047, d = col - 2048;
                    bf16x4v pk;
                    #pragma unroll
                    for (int r = 0; r < 4; ++r) pk[r] = (bf16)(acc[m][n][r] + bb);
                    *(bf16x4v*)&vT[((size_t)batch << 21) + ((size_t)d << 11) + s] = pk;
                }
            } else {
                #pragma unroll
                for (int r = 0; r < 4; ++r)
                    C[(size_t)(gm + r) * N + col] = (OutT)(acc[m][n][r] * scale);
            }
        }
    }
}

// ---------------------------------------------------------------------------
// Row softmax in-place over bf16 scores; rows of length 2048, 1 block/row.
// ---------------------------------------------------------------------------
__global__ __launch_bounds__(256)
void softmax_inplace(bf16* __restrict__ sc)
{
    __shared__ float red[8];
    bf16* row = sc + (size_t)blockIdx.x * 2048;
    const int t = threadIdx.x;
    const int lane = t & 63;
    const int wid = t >> 6;

    bf16x8v v = *(const bf16x8v*)(row + t * 8);
    float f[8];
    #pragma unroll
    for (int j = 0; j < 8; ++j) f[j] = (float)v[j];

    float m = f[0];
    #pragma unroll
    for (int j = 1; j < 8; ++j) m = fmaxf(m, f[j]);
    #pragma unroll
    for (int off = 32; off >= 1; off >>= 1) m = fmaxf(m, __shfl_xor(m, off));
    if (lane == 0) red[wid] = m;
    __syncthreads();
    m = fmaxf(fmaxf(red[0], red[1]), fmaxf(red[2], red[3]));

    float s = 0.f;
    #pragma unroll
    for (int j = 0; j < 8; ++j) { f[j] = __expf(f[j] - m); s += f[j]; }
    #pragma unroll
    for (int off = 32; off >= 1; off >>= 1) s += __shfl_xor(s, off);
    if (lane == 0) red[4 + wid] = s;
    __syncthreads();
    s = red[4] + red[5] + red[6] + red[7];

    const float inv = 1.0f / s;
    bf16x8v o;
    #pragma unroll
    for (int j = 0; j < 8; ++j) o[j] = (bf16)(f[j] * inv);
    *(bf16x8v*)(row + t * 8) = o;
}

// ---------------------------------------------------------------------------
extern "C" void kernel_launch(void* const* d_in, const int* in_sizes, int n_in,
                              void* d_out, int out_size, void* d_ws, size_t ws_size,
                              hipStream_t stream)
{
    const float* x1 = (const float*)d_in[0];
    const float* Wq = (const float*)d_in[1];
    const float* bq = (const float*)d_in[2];
    const float* Wk = (const float*)d_in[3];
    const float* bk = (const float*)d_in[4];
    const float* Wv = (const float*)d_in[5];
    const float* bv = (const float*)d_in[6];
    float* out = (float*)d_out;

    // workspace layout (bf16 elements unless noted)
    bf16* xb     = (bf16*)d_ws;             // 8388608
    bf16* wb     = xb + NX;                 // 3*1048576 (Wq,Wk,Wv rows x 1024)
    bf16* qkb    = wb + 3 * NW;             // 2*8388608 (q then k)
    bf16* vTb    = qkb + 2 * (size_t)NX;    // 8388608 (V^T per batch [D][S])
    bf16* scores = vTb + NX;                // 4*2048*2048
    float* biases = (float*)(scores + 4 * (size_t)SB * SB); // 3072 f32

    // 1. convert inputs to bf16
    convert_kernel<<<dim3(2048), dim3(256), 0, stream>>>(
        x1, Wq, Wk, Wv, bq, bk, bv, xb, wb, biases);

    // 2. fused QKV projection: M=8192, N=3072 (q|k|vT), K=1024
    gemm_bt<0, bf16><<<dim3(24, 64, 1), dim3(256), 0, stream>>>(
        xb, wb, qkb, vTb, biases, 1024, 1024, 0L, 0L, 0L, 1.0f);

    // 3. scores = Q K^T / 32 per batch: M=N=2048, K=1024, z=4
    gemm_bt<1, bf16><<<dim3(16, 16, 4), dim3(256), 0, stream>>>(
        qkb, qkb + NX, scores, nullptr, nullptr, SB, DD,
        (long)(SB * DD), (long)(SB * DD), (long)(SB * SB), 1.0f / 32.0f);

    // 4. softmax rows in-place
    softmax_inplace<<<dim3(4 * SB), dim3(256), 0, stream>>>(scores);

    // 5. out = P V per batch: M=2048, N=1024, K=2048, z=4, fp32 out
    gemm_bt<2, float><<<dim3(8, 16, 4), dim3(256), 0, stream>>>(
        scores, vTb, out, nullptr, nullptr, DD, SB,
        (long)(SB * SB), (long)(SB * DD), (long)(SB * DD), 1.0f);
}